// Round 3
// baseline (94184.247 us; speedup 1.0000x reference)
//
#include <hip/hip_runtime.h>
#include <cstdint>
#include <cstddef>

// PlainRNN fused: h_{t+1} = tanh(h_t @ W_eff + b_eff), traj[t] = h_t @ W_h2o + b_h2o
// W_eff = W_h2h + W_h2o @ W_i2h  (recurrence composition removes x from the loop)
//
// Persistent kernel: 16 groups (16 batch rows each) x 16 blocks (72 of 1152 cols each).
// Groups formed DYNAMICALLY per-XCD (HW_REG_XCC_ID + per-XCD slot counter): all 16
// members share one XCD L2 BY CONSTRUCTION.
//
// R8: flags ride the XCD-L2 path (same mechanism as the h data), not agent scope.
//   Evidence: R6's poll flood raised FETCH_SIZE (EA/HBM traffic) by 10.7MB =>
//   agent-scope ops travel past the XCD L2 to the fabric coherence point
//   (per-XCD L2s are non-coherent, so the AGENT coherence point is beyond them).
//   That EA round trip sat on the serial step path twice (store propagate +
//   poll detect) = the ~2us/step my stage budget couldn't explain.
//   Since the group is same-XCD, flags only need XCD-L2 coherence:
//     arrival: tid0 PLAIN store of t (vL1 is write-through -> lands in XCD L2;
//              issued after the drain barrier so h stores are already acked).
//              One 128B line PER MEMBER (no line sharing with other stores/polls).
//     poll:    wave0 only, lanes 0..15 poll the 16 member lines with inline-asm
//              `global_load_dword ... sc0` = L1-bypass, XCD-L2-served (NOT sc1 =
//              no fabric trip). s_sleep(1) backoff, tries-bounded (absmax-visible
//              failure mode, never a hang). R4's freeze was a NON-bypassing load
//              (L1 line stays MRU while polled => stale forever); sc0 avoids it.
//   h data unchanged: plain stores -> XCD L2 (syncthreads drains vmcnt); consumers
//   use PLAIN loads + 4-slot hbuf rotation (128KB/step streams the 32KB L1 =>
//   A-lines capacity-evicted => loads miss L1, hit shared L2 fresh).
//   beff hoisted to registers (bown).
// History: R5 atomicAdd+serial poll 1600us; R6 per-wave flags, 1024 pollers no
//   backoff 3667us (EA flood); R7 store-flag + wave0 poll w/ backoff 1452us.

#define BATCH  256
#define INPUT  128
#define HIDDEN 1024
#define OUTPUT 128
#define TSTEPS 512
#define NCAT   1152
#define NTILE  72
#define GROUPS 16
#define MEMB   16
#define NSLOT  4

// workspace layout (bytes)
#define WS_WFRAG 0u
#define WS_BEFF  2621440u
#define WS_HBUF  2629632u                 // 4 slots x 256x1024 f16 = 4x524288
#define WS_BAR   4726784u
// bar[] u32: [(g*16+mem)*32]  per-member step flag, ONE 128B LINE EACH (16x16 lines)
//            [8192 + xcc*32]  per-XCD slot counters (one-time)
#define BAR_U32S 8448

typedef _Float16 f16;
typedef _Float16 v8h __attribute__((ext_vector_type(8)));
typedef float    v4f __attribute__((ext_vector_type(4)));

__device__ __forceinline__ float fast_tanh(float x){
  float e = __expf(2.0f * x);
  return (e - 1.0f) / (e + 1.0f);
}

// L1-bypassing, XCD-L2-served load (sc0 only: no sc1 => no fabric/EA trip).
__device__ __forceinline__ unsigned load_flag_l2(const unsigned* p){
  unsigned v;
  asm volatile("global_load_dword %0, %1, off sc0\n\t"
               "s_waitcnt vmcnt(0)"
               : "=v"(v) : "v"(p) : "memory");
  return v;
}

// ---- bias composition
__global__ void k_bias(const float* __restrict__ bi2h, const float* __restrict__ bh2h,
                       const float* __restrict__ bh2o, const float* __restrict__ Wi2h,
                       float* __restrict__ beff){
  int n = blockIdx.x*256 + threadIdx.x;
  if (n >= 1168) return;
  float v = 0.f;
  if (n < HIDDEN){
    v = bi2h[n] + bh2h[n];
    for (int j=0;j<INPUT;j++) v += bh2o[j]*Wi2h[j*HIDDEN + n];
  } else if (n < NCAT){
    v = bh2o[n - HIDDEN];
  }
  beff[n] = v;
}

// ---- h_1 = tanh(x0 @ W_i2h + b_i2h + b_h2h) -> slot 0
__global__ void k_h1(const float* __restrict__ x0, const float* __restrict__ Wi2h,
                     const float* __restrict__ bi2h, const float* __restrict__ bh2h,
                     f16* __restrict__ hbuf){
  int idx = blockIdx.x*256 + threadIdx.x;
  int m = idx >> 10, n = idx & 1023;
  float acc = bi2h[n] + bh2h[n];
  const float* xr = x0 + m*INPUT;
  for (int j=0;j<INPUT;j++) acc += xr[j]*Wi2h[j*HIDDEN + n];
  hbuf[idx] = (f16)fast_tanh(acc);
}

// ---- traj[0] = x_0
__global__ void k_copy0(const float* __restrict__ x0, float* __restrict__ out){
  int i = blockIdx.x*256 + threadIdx.x;
  out[i] = x0[i];
}

// ---- W fragment packing: [mem 16][wave 4][kk 8][c 5][lane 64][8 halves]
__global__ void k_wfrag(const float* __restrict__ Wh2h, const float* __restrict__ Wh2o,
                        const float* __restrict__ Wi2h, f16* __restrict__ Wfrag){
  int gid = blockIdx.x*256 + threadIdx.x;
  int lane = gid & 63;
  int fi = gid >> 6;
  int c = fi % 5, kk = (fi/5) & 7, wv = (fi/40) & 3, mem = fi/160;
  int k0 = wv*256 + kk*32 + (lane>>4)*8;
  int n  = mem*NTILE + c*16 + (lane & 15);
  f16 vals[8];
  if (n >= NCAT){
    #pragma unroll
    for (int j=0;j<8;j++) vals[j] = (f16)0.f;
  } else if (n >= HIDDEN){
    #pragma unroll
    for (int j=0;j<8;j++) vals[j] = (f16)Wh2o[(k0+j)*OUTPUT + (n-HIDDEN)];
  } else {
    float acc[8];
    #pragma unroll
    for (int j=0;j<8;j++) acc[j] = Wh2h[(k0+j)*HIDDEN + n];
    for (int q=0;q<INPUT;q++){
      float wi = Wi2h[q*HIDDEN + n];
      #pragma unroll
      for (int j=0;j<8;j++) acc[j] += Wh2o[(k0+j)*OUTPUT + q]*wi;
    }
    #pragma unroll
    for (int j=0;j<8;j++) vals[j] = (f16)acc[j];
  }
  v8h pack;
  #pragma unroll
  for (int j=0;j<8;j++) pack[j] = vals[j];
  *(v8h*)(Wfrag + (size_t)gid*8) = pack;
}

// ---- persistent recurrence kernel: 256 blocks x 256 threads, 1 block/CU (96KB dyn LDS)
__global__ void __launch_bounds__(256, 1)
k_rnn(const f16* __restrict__ Wfrag, const float* __restrict__ beff,
      f16* __restrict__ hbuf, unsigned int* __restrict__ bar,
      float* __restrict__ out){
  extern __shared__ char lds_raw[];
  float*    red    = (float*)lds_raw;              // [(c*3+rank)][lane][4] f32, 15360 B
  unsigned* s_slot = (unsigned*)(lds_raw + 16384);

  const int tid  = threadIdx.x;
  const int lane = tid & 63;
  const int wv   = tid >> 6;

  // Dynamic same-XCD group formation. 1 block/CU + grid==CU count => 32 blocks/XCD.
  // Group = xcc*2 + slot/16, member = slot%16: group shares one XCD L2 BY CONSTRUCTION.
  if (tid == 0){
    unsigned xcc;
    asm volatile("s_getreg_b32 %0, hwreg(HW_REG_XCC_ID)" : "=s"(xcc));
    xcc &= 7;
    unsigned slot = atomicAdd(&bar[8192 + xcc*32], 1u);  // one-time, device-scope
    *s_slot = xcc*32 + (slot & 31u);
  }
  __syncthreads();
  const unsigned sid = *s_slot;
  const int g   = sid >> 4;
  const int mem = sid & 15;
  if (g >= GROUPS) return;
  const int m0   = g * 16;
  const int n0   = mem * NTILE;
  const int quad = lane >> 4;
  const int l15  = lane & 15;

  // B fragments resident in registers for the whole 511-step loop
  v8h bw[8][5];
  {
    const f16* wp = Wfrag + ((size_t)((mem*4 + wv)*40)*64 + lane)*8;
    #pragma unroll
    for (int kk=0;kk<8;kk++)
      #pragma unroll
      for (int c=0;c<5;c++)
        bw[kk][c] = *(const v8h*)(wp + (size_t)((kk*5+c)*64)*8);
  }

  // Per-thread bias for owned columns hoisted into registers (beff load always
  // missed L1 — the A-stream evicts it — and sat on the post-reduce path).
  float bown[2] = {0.f, 0.f};
  #pragma unroll
  for (int c=0;c<5;c++){
    if ((c & 3) == wv){
      int colT = c*16 + l15;
      int col  = n0 + colT;
      if (colT < NTILE && col < NCAT) bown[c>>2] = beff[col];
    }
  }

  const int kbase = wv*256;
  unsigned int* flg = bar + (size_t)g*16*32;   // 16 member flags, one 128B line each

  for (int t=1; t<TSTEPS; ++t){
    // ---- wait: all 16 member flags >= t-1. Wave 0 only; lanes 0-15 poll the 16
    // member lines with sc0 loads (L1-bypass, XCD-L2-served — no fabric trip),
    // s_sleep(1) backoff. 16 lines => 16 parallel L2 bank requests per round.
    if (wv == 0){
      const unsigned target = (unsigned)(t-1);
      const unsigned* fp = flg + (size_t)(lane & 15)*32;
      unsigned tries = 0;
      for (;;){
        unsigned f = load_flag_l2(fp);
        if (__all((int)(f >= target))) break;
        if (++tries > 2048u) break;
        __builtin_amdgcn_s_sleep(1);
      }
    }
    __syncthreads();   // release: waves 1-3 park here while wave 0 polls

    const f16* hin  = hbuf + (size_t)((t-1)&(NSLOT-1))*(BATCH*HIDDEN);
    f16*       hout = hbuf + (size_t)(t&(NSLOT-1))*(BATCH*HIDDEN);

    // A fragments: plain vector loads. 4-slot rotation guarantees the L1 line for
    // this address was evicted (128KB/step streamed) => miss L1, hit shared L2.
    // lane holds A[m=lane&15][k=quad*8+j]; waves read disjoint K slices.
    v8h af[8];
    {
      const v8h* abase = (const v8h*)(hin + (size_t)(m0 + l15)*HIDDEN + kbase + quad*8);
      #pragma unroll
      for (int kk=0;kk<8;kk++)
        af[kk] = abase[kk*4];            // stride 32 halves = 4 v8h
    }

    v4f acc[5];
    #pragma unroll
    for (int c=0;c<5;c++){ v4f z = {0.f,0.f,0.f,0.f}; acc[c] = z; }

    #pragma unroll
    for (int kk=0;kk<8;kk++){
      #pragma unroll
      for (int c=0;c<5;c++)
        acc[c] = __builtin_amdgcn_mfma_f32_16x16x32_f16(af[kk], bw[kk][c], acc[c], 0,0,0);
    }

    // cross-wave K reduction via LDS. tile c owner = c&3.
    #pragma unroll
    for (int c=0;c<5;c++){
      int owner = c & 3;
      if (wv != owner){
        int rank = (wv > owner) ? wv-1 : wv;
        *(v4f*)(red + ((size_t)(c*3 + rank)*64 + lane)*4) = acc[c];
      }
    }
    __syncthreads();   // reduce visibility

    // pass 1: hidden columns (consumed by group next step) -> plain stores into L2
    #pragma unroll
    for (int c=0;c<5;c++){
      if ((c & 3) == wv){
        int colT = c*16 + l15;
        int col  = n0 + colT;
        if (col < HIDDEN && colT < NTILE){
          v4f s = acc[c];
          #pragma unroll
          for (int r=0;r<3;r++) s += *(const v4f*)(red + ((size_t)(c*3 + r)*64 + lane)*4);
          float b = bown[c>>2];
          #pragma unroll
          for (int r=0;r<4;r++){
            float v = fast_tanh(s[r] + b);
            hout[(size_t)(m0 + quad*4 + r)*HIDDEN + col] = (f16)v;  // C/D: col=lane&15,row=quad*4+r
          }
        }
      }
    }
    __syncthreads();   // drain: each wave waits vmcnt(0) => h stores are in L2

    // arrival: PLAIN store (vL1 write-through -> XCD L2). h stores already acked
    // by the drain barrier, so L2 order is h-then-flag. Own line, no contention.
    if (tid == 0)
      *(volatile unsigned*)(flg + (size_t)mem*32) = (unsigned)t;

    // pass 2: y columns (consumed by nobody) — off the critical path, overlaps
    // group-mates' polling. red stable until next step's post-release writes.
    #pragma unroll
    for (int c=0;c<5;c++){
      if ((c & 3) == wv){
        int colT = c*16 + l15;
        int col  = n0 + colT;
        if (col >= HIDDEN && colT < NTILE){
          v4f s = acc[c];
          #pragma unroll
          for (int r=0;r<3;r++) s += *(const v4f*)(red + ((size_t)(c*3 + r)*64 + lane)*4);
          float b = bown[c>>2];
          float* op = out + (size_t)t*(BATCH*OUTPUT) + (col - HIDDEN);
          #pragma unroll
          for (int r=0;r<4;r++)
            op[(size_t)(m0 + quad*4 + r)*OUTPUT] = s[r] + b;
        }
      }
    }
  }
}

extern "C" void kernel_launch(void* const* d_in, const int* in_sizes, int n_in,
                              void* d_out, int out_size, void* d_ws, size_t ws_size,
                              hipStream_t stream){
  const float* x0   = (const float*)d_in[0];
  const float* Wi2h = (const float*)d_in[1];
  const float* bi2h = (const float*)d_in[2];
  const float* Wh2h = (const float*)d_in[3];
  const float* bh2h = (const float*)d_in[4];
  const float* Wh2o = (const float*)d_in[5];
  const float* bh2o = (const float*)d_in[6];
  float* out = (float*)d_out;
  char* ws = (char*)d_ws;

  f16*          Wfrag = (f16*)(ws + WS_WFRAG);
  float*        beff  = (float*)(ws + WS_BEFF);
  f16*          hbuf  = (f16*)(ws + WS_HBUF);
  unsigned int* bar   = (unsigned int*)(ws + WS_BAR);

  hipMemsetAsync(bar, 0, BAR_U32S*sizeof(unsigned int), stream);
  k_bias <<<5,    256, 0, stream>>>(bi2h, bh2h, bh2o, Wi2h, beff);
  k_h1   <<<1024, 256, 0, stream>>>(x0, Wi2h, bi2h, bh2h, hbuf);
  k_copy0<<<128,  256, 0, stream>>>(x0, out);
  k_wfrag<<<640,  256, 0, stream>>>(Wh2h, Wh2o, Wi2h, Wfrag);

  // 96KB dynamic LDS forces 1 block/CU -> all 256 blocks co-resident, 32 per XCD,
  // 1 wave/SIMD -> full VGPR budget for register-resident W fragments.
  hipFuncSetAttribute((const void*)k_rnn, hipFuncAttributeMaxDynamicSharedMemorySize, 98304);
  k_rnn<<<256, 256, 98304, stream>>>(Wfrag, beff, hbuf, bar, out);
}

// Round 4
// 2251.561 us; speedup vs baseline: 41.8306x; 41.8306x over previous
//
#include <hip/hip_runtime.h>
#include <cstdint>
#include <cstddef>

// PlainRNN fused: h_{t+1} = tanh(h_t @ W_eff + b_eff), traj[t] = h_t @ W_h2o + b_h2o
// W_eff = W_h2h + W_h2o @ W_i2h  (recurrence composition removes x from the loop)
//
// R9: TWO-CHAIN INTERLEAVE — hide the flag-propagation latency, don't fight it.
//   Learned so far:
//     R5 1600us: atomicAdd+poll works (agent scope both sides).
//     R6 3667us: unthrottled 64-lane agent polls flood the fabric (FETCH +10.7MB).
//     R7 1452us: store-flag arrival + wave0 throttled poll. ~2us/step still sync.
//     R8 94ms:  FALSIFIED "sc0 load can see plain cross-CU stores" — poll never
//               succeeded (full 2048-try spin every step). Flag visibility NEEDS
//               the agent-scope path (fabric coherence point, ~1-2us RT).
//   R9: the 16 row-groups are INDEPENDENT recurrences (h row m depends only on
//   h row m). Each block runs member `mem` of TWO groups: gA=xcc, gB=xcc+8.
//   Same column slice => same register-resident W fragments + bias for both.
//   Loop: pollA -> bodyA -> flagA -> pollB -> bodyB -> flagB. Each chain's flag
//   gets a full other-chain body (~1us) to propagate before its poll => exposed
//   wait ~0 if one-way propagation < body time.
//   Barrier mechanism FROZEN at R7's proven form: agent atomic store arrival,
//   wave0-only agent atomic-load poll, s_sleep(1) backoff, tries-bounded.
//   Placement: grid=256 (1 block/CU via 96KB LDS) => exactly 32 blocks/XCD =>
//   slots 0..15 active (16 members/XCD), slots 16..31 exit. Same-XCD groups by
//   construction, 128 active blocks, 2 chains each = all 16 groups covered.
//   h data: plain stores -> XCD L2 (drain syncthreads = per-wave vmcnt(0));
//   consumers PLAIN loads + 4-slot hbuf rotation (streams the 32KB L1 => A-lines
//   capacity-evicted => L1 miss, shared-L2 hit, always fresh).

#define BATCH  256
#define INPUT  128
#define HIDDEN 1024
#define OUTPUT 128
#define TSTEPS 512
#define NCAT   1152
#define NTILE  72
#define GROUPS 16
#define MEMB   16
#define NSLOT  4

// workspace layout (bytes)
#define WS_WFRAG 0u
#define WS_BEFF  2621440u
#define WS_HBUF  2629632u                 // 4 slots x 256x1024 f16 = 4x524288
#define WS_BAR   4726784u
// bar[] u32: [g*32 + mem]   per-member step flags (one 128B line per group)
//            [512 + xcc*32] per-XCD slot counters (one-time)
#define BAR_U32S 768

typedef _Float16 f16;
typedef _Float16 v8h __attribute__((ext_vector_type(8)));
typedef float    v4f __attribute__((ext_vector_type(4)));

__device__ __forceinline__ float fast_tanh(float x){
  float e = __expf(2.0f * x);
  return (e - 1.0f) / (e + 1.0f);
}

// ---- bias composition
__global__ void k_bias(const float* __restrict__ bi2h, const float* __restrict__ bh2h,
                       const float* __restrict__ bh2o, const float* __restrict__ Wi2h,
                       float* __restrict__ beff){
  int n = blockIdx.x*256 + threadIdx.x;
  if (n >= 1168) return;
  float v = 0.f;
  if (n < HIDDEN){
    v = bi2h[n] + bh2h[n];
    for (int j=0;j<INPUT;j++) v += bh2o[j]*Wi2h[j*HIDDEN + n];
  } else if (n < NCAT){
    v = bh2o[n - HIDDEN];
  }
  beff[n] = v;
}

// ---- h_1 = tanh(x0 @ W_i2h + b_i2h + b_h2h) -> slot 0
__global__ void k_h1(const float* __restrict__ x0, const float* __restrict__ Wi2h,
                     const float* __restrict__ bi2h, const float* __restrict__ bh2h,
                     f16* __restrict__ hbuf){
  int idx = blockIdx.x*256 + threadIdx.x;
  int m = idx >> 10, n = idx & 1023;
  float acc = bi2h[n] + bh2h[n];
  const float* xr = x0 + m*INPUT;
  for (int j=0;j<INPUT;j++) acc += xr[j]*Wi2h[j*HIDDEN + n];
  hbuf[idx] = (f16)fast_tanh(acc);
}

// ---- traj[0] = x_0
__global__ void k_copy0(const float* __restrict__ x0, float* __restrict__ out){
  int i = blockIdx.x*256 + threadIdx.x;
  out[i] = x0[i];
}

// ---- W fragment packing: [mem 16][wave 4][kk 8][c 5][lane 64][8 halves]
__global__ void k_wfrag(const float* __restrict__ Wh2h, const float* __restrict__ Wh2o,
                        const float* __restrict__ Wi2h, f16* __restrict__ Wfrag){
  int gid = blockIdx.x*256 + threadIdx.x;
  int lane = gid & 63;
  int fi = gid >> 6;
  int c = fi % 5, kk = (fi/5) & 7, wv = (fi/40) & 3, mem = fi/160;
  int k0 = wv*256 + kk*32 + (lane>>4)*8;
  int n  = mem*NTILE + c*16 + (lane & 15);
  f16 vals[8];
  if (n >= NCAT){
    #pragma unroll
    for (int j=0;j<8;j++) vals[j] = (f16)0.f;
  } else if (n >= HIDDEN){
    #pragma unroll
    for (int j=0;j<8;j++) vals[j] = (f16)Wh2o[(k0+j)*OUTPUT + (n-HIDDEN)];
  } else {
    float acc[8];
    #pragma unroll
    for (int j=0;j<8;j++) acc[j] = Wh2h[(k0+j)*HIDDEN + n];
    for (int q=0;q<INPUT;q++){
      float wi = Wi2h[q*HIDDEN + n];
      #pragma unroll
      for (int j=0;j<8;j++) acc[j] += Wh2o[(k0+j)*OUTPUT + q]*wi;
    }
    #pragma unroll
    for (int j=0;j<8;j++) vals[j] = (f16)acc[j];
  }
  v8h pack;
  #pragma unroll
  for (int j=0;j<8;j++) pack[j] = vals[j];
  *(v8h*)(Wfrag + (size_t)gid*8) = pack;
}

// One chain step (poll -> load A -> MFMA -> reduce -> store h -> flag -> y-out).
// Everything chain-specific comes in via the macro args; af/acc are scoped so
// the second chain reuses the same registers.
#define CHAIN_STEP(M0X, REDX, FLGX)                                              \
  do {                                                                           \
    if (wv == 0){                                                                \
      const unsigned target = (unsigned)(t-1);                                   \
      unsigned tries = 0;                                                        \
      for (;;){                                                                  \
        unsigned f = __hip_atomic_load((FLGX) + (lane & 15), __ATOMIC_RELAXED,   \
                                       __HIP_MEMORY_SCOPE_AGENT);                \
        if (__all((int)(f >= target))) break;                                    \
        if (++tries > 2048u) break;                                              \
        __builtin_amdgcn_s_sleep(1);                                             \
      }                                                                          \
    }                                                                            \
    __syncthreads();   /* release: waves 1-3 park while wave 0 polls */          \
    const f16* hin  = hbuf + (size_t)((t-1)&(NSLOT-1))*(BATCH*HIDDEN);           \
    f16*       hout = hbuf + (size_t)(t&(NSLOT-1))*(BATCH*HIDDEN);               \
    v8h af[8];                                                                   \
    {                                                                            \
      const v8h* abase = (const v8h*)(hin + (size_t)((M0X) + l15)*HIDDEN         \
                                      + kbase + quad*8);                         \
      _Pragma("unroll")                                                          \
      for (int kk=0;kk<8;kk++) af[kk] = abase[kk*4];                             \
    }                                                                            \
    v4f acc[5];                                                                  \
    _Pragma("unroll")                                                            \
    for (int c=0;c<5;c++){ v4f z = {0.f,0.f,0.f,0.f}; acc[c] = z; }              \
    _Pragma("unroll")                                                            \
    for (int kk=0;kk<8;kk++){                                                    \
      _Pragma("unroll")                                                          \
      for (int c=0;c<5;c++)                                                      \
        acc[c] = __builtin_amdgcn_mfma_f32_16x16x32_f16(af[kk], bw[kk][c],       \
                                                        acc[c], 0,0,0);          \
    }                                                                            \
    _Pragma("unroll")                                                            \
    for (int c=0;c<5;c++){                                                       \
      int owner = c & 3;                                                         \
      if (wv != owner){                                                          \
        int rank = (wv > owner) ? wv-1 : wv;                                     \
        *(v4f*)((REDX) + ((size_t)(c*3 + rank)*64 + lane)*4) = acc[c];           \
      }                                                                          \
    }                                                                            \
    __syncthreads();   /* reduce visibility */                                   \
    _Pragma("unroll")                                                            \
    for (int c=0;c<5;c++){                                                       \
      if ((c & 3) == wv){                                                        \
        int colT = c*16 + l15;                                                   \
        int col  = n0 + colT;                                                    \
        if (col < HIDDEN && colT < NTILE){                                       \
          v4f s = acc[c];                                                        \
          _Pragma("unroll")                                                      \
          for (int r=0;r<3;r++)                                                  \
            s += *(const v4f*)((REDX) + ((size_t)(c*3 + r)*64 + lane)*4);        \
          float b = bown[c>>2];                                                  \
          _Pragma("unroll")                                                      \
          for (int r=0;r<4;r++){                                                 \
            float v = fast_tanh(s[r] + b);                                       \
            hout[(size_t)((M0X) + quad*4 + r)*HIDDEN + col] = (f16)v;            \
          }                                                                      \
        }                                                                        \
      }                                                                          \
    }                                                                            \
    __syncthreads();   /* drain: per-wave vmcnt(0) => h stores are in L2 */      \
    if (tid == 0)                                                                \
      __hip_atomic_store((FLGX) + mem, (unsigned)t, __ATOMIC_RELAXED,            \
                         __HIP_MEMORY_SCOPE_AGENT);                              \
    _Pragma("unroll")                                                            \
    for (int c=0;c<5;c++){                                                       \
      if ((c & 3) == wv){                                                        \
        int colT = c*16 + l15;                                                   \
        int col  = n0 + colT;                                                    \
        if (col >= HIDDEN && colT < NTILE){                                      \
          v4f s = acc[c];                                                        \
          _Pragma("unroll")                                                      \
          for (int r=0;r<3;r++)                                                  \
            s += *(const v4f*)((REDX) + ((size_t)(c*3 + r)*64 + lane)*4);        \
          float b = bown[c>>2];                                                  \
          float* op = out + (size_t)t*(BATCH*OUTPUT) + (col - HIDDEN);           \
          _Pragma("unroll")                                                      \
          for (int r=0;r<4;r++)                                                  \
            op[(size_t)((M0X) + quad*4 + r)*OUTPUT] = s[r] + b;                  \
        }                                                                        \
      }                                                                          \
    }                                                                            \
  } while(0)

// ---- persistent recurrence kernel: 256 blocks x 256 threads, 1 block/CU (96KB dyn LDS)
// 128 active blocks (slots 0..15 per XCD), each running TWO chains.
__global__ void __launch_bounds__(256, 1)
k_rnn(const f16* __restrict__ Wfrag, const float* __restrict__ beff,
      f16* __restrict__ hbuf, unsigned int* __restrict__ bar,
      float* __restrict__ out){
  extern __shared__ char lds_raw[];
  float*    redA   = (float*)lds_raw;               // 15360 B used
  float*    redB   = (float*)(lds_raw + 16384);     // 15360 B used
  unsigned* s_slot = (unsigned*)(lds_raw + 32768);

  const int tid  = threadIdx.x;
  const int lane = tid & 63;
  const int wv   = tid >> 6;

  // Dynamic same-XCD placement. grid=256 @ 1 block/CU => exactly 32 blocks/XCD.
  // Slots 0..15 active: member=slot, chains gA=xcc, gB=xcc+8. Slots 16..31 exit.
  if (tid == 0){
    unsigned xcc;
    asm volatile("s_getreg_b32 %0, hwreg(HW_REG_XCC_ID)" : "=s"(xcc));
    xcc &= 7;
    unsigned slot = atomicAdd(&bar[512 + xcc*32], 1u);  // one-time, device-scope
    *s_slot = xcc*32 + (slot & 31u);
  }
  __syncthreads();
  const unsigned sid = *s_slot;
  const int xcc  = sid >> 5;
  const int slot = sid & 31;
  if (slot >= MEMB) return;
  const int mem = slot;
  const int gA  = xcc;          // groups 0..7  = batch rows 0..127
  const int gB  = xcc + 8;      // groups 8..15 = batch rows 128..255
  const int m0A = gA * 16;
  const int m0B = gB * 16;
  const int n0   = mem * NTILE;
  const int quad = lane >> 4;
  const int l15  = lane & 15;

  // B fragments resident in registers; SHARED by both chains (same col slice).
  v8h bw[8][5];
  {
    const f16* wp = Wfrag + ((size_t)((mem*4 + wv)*40)*64 + lane)*8;
    #pragma unroll
    for (int kk=0;kk<8;kk++)
      #pragma unroll
      for (int c=0;c<5;c++)
        bw[kk][c] = *(const v8h*)(wp + (size_t)((kk*5+c)*64)*8);
  }

  // Bias hoisted to registers; shared by both chains (same cols).
  float bown[2] = {0.f, 0.f};
  #pragma unroll
  for (int c=0;c<5;c++){
    if ((c & 3) == wv){
      int colT = c*16 + l15;
      int col  = n0 + colT;
      if (colT < NTILE && col < NCAT) bown[c>>2] = beff[col];
    }
  }

  const int kbase = wv*256;
  unsigned int* flgA = bar + gA*32;   // 16 member flags, one 128B line per group
  unsigned int* flgB = bar + gB*32;

  for (int t=1; t<TSTEPS; ++t){
    // Chain A: its flags had the whole previous B-body (+ iteration tail) to
    // propagate; chain B: a whole A-body. Exposed wait ~0 if one-way
    // propagation < body time.
    CHAIN_STEP(m0A, redA, flgA);
    CHAIN_STEP(m0B, redB, flgB);
  }
}

extern "C" void kernel_launch(void* const* d_in, const int* in_sizes, int n_in,
                              void* d_out, int out_size, void* d_ws, size_t ws_size,
                              hipStream_t stream){
  const float* x0   = (const float*)d_in[0];
  const float* Wi2h = (const float*)d_in[1];
  const float* bi2h = (const float*)d_in[2];
  const float* Wh2h = (const float*)d_in[3];
  const float* bh2h = (const float*)d_in[4];
  const float* Wh2o = (const float*)d_in[5];
  const float* bh2o = (const float*)d_in[6];
  float* out = (float*)d_out;
  char* ws = (char*)d_ws;

  f16*          Wfrag = (f16*)(ws + WS_WFRAG);
  float*        beff  = (float*)(ws + WS_BEFF);
  f16*          hbuf  = (f16*)(ws + WS_HBUF);
  unsigned int* bar   = (unsigned int*)(ws + WS_BAR);

  hipMemsetAsync(bar, 0, BAR_U32S*sizeof(unsigned int), stream);
  k_bias <<<5,    256, 0, stream>>>(bi2h, bh2h, bh2o, Wi2h, beff);
  k_h1   <<<1024, 256, 0, stream>>>(x0, Wi2h, bi2h, bh2h, hbuf);
  k_copy0<<<128,  256, 0, stream>>>(x0, out);
  k_wfrag<<<640,  256, 0, stream>>>(Wh2h, Wh2o, Wi2h, Wfrag);

  // 96KB dynamic LDS forces 1 block/CU -> 256 blocks co-resident, exactly 32
  // per XCD (the placement invariant the dynamic grouping relies on).
  hipFuncSetAttribute((const void*)k_rnn, hipFuncAttributeMaxDynamicSharedMemorySize, 98304);
  k_rnn<<<256, 256, 98304, stream>>>(Wfrag, beff, hbuf, bar, out);
}